// Round 2
// baseline (376.230 us; speedup 1.0000x reference)
//
#include <hip/hip_runtime.h>

// ODE_23390391894829: batched RK4 integration of constant-curvature rod.
// Reference quirks replicated:
//  - actions[:,3:6] are NEVER used (reference loop re-reads segment 0 at n=0).
//  - lengths for BOTH segments come from l = L0 + actions[:,0].
//  - segment 2 continues the same trajectory (autonomous ODE, constant u).
// Output: (2T, B, 14) fp32, out[t] = traj[min(t,L)] per segment.
//
// R2->R3: remove the per-row __syncthreads. The block-wide barrier made the
// compiler emit s_waitcnt vmcnt(0) before s_barrier every row -> all global
// stores drained 26x per block, stores never pipelined across rows
// (~3 TB/s effective write BW vs 6.3 achievable). The transpose only needs a
// WAVE-local exchange: each wave stages its 64x14 floats in a private LDS
// region (its global chunk 64*14*4 = 3584 B is contiguous), orders the
// exchange with a wave-local s_waitcnt lgkmcnt(0), and issues nontemporal
// stores that stay in flight across rows. Double-buffered per-wave regions
// so row t's outstanding ds_reads never race row t+1's ds_writes.
// R3->R4: compile fix only — __builtin_nontemporal_store requires a native
// vector type, not HIP's float4 class. Use ext_vector_type(4) float.

#define C_L0 0.05f
#define C_D  0.0075f
#define C_DS 0.005f
#define NB   256   // batch elements per block == block size (4 waves)

typedef float f32x4 __attribute__((ext_vector_type(4)));
typedef float f32x2 __attribute__((ext_vector_type(2)));

__device__ __forceinline__ void ode_f(const float* __restrict__ y, float ux, float uy,
                                      float* __restrict__ d) {
    d[0] = y[5];
    d[1] = y[8];
    d[2] = y[11];
#pragma unroll
    for (int i = 0; i < 3; ++i) {
        float Ri0 = y[3 + 3 * i + 0];
        float Ri1 = y[3 + 3 * i + 1];
        float Ri2 = y[3 + 3 * i + 2];
        d[3 + 3 * i + 0] = -uy * Ri2;
        d[3 + 3 * i + 1] =  ux * Ri2;
        d[3 + 3 * i + 2] =  uy * Ri0 - ux * Ri1;
    }
}

__device__ __forceinline__ void rk4_step(float* __restrict__ y, float ux, float uy) {
    const float h = C_DS;
    float k1[12], k2[12], k3[12], k4[12], t[12];
    ode_f(y, ux, uy, k1);
#pragma unroll
    for (int i = 0; i < 12; ++i) t[i] = y[i] + (0.5f * h) * k1[i];
    ode_f(t, ux, uy, k2);
#pragma unroll
    for (int i = 0; i < 12; ++i) t[i] = y[i] + (0.5f * h) * k2[i];
    ode_f(t, ux, uy, k3);
#pragma unroll
    for (int i = 0; i < 12; ++i) t[i] = y[i] + h * k3[i];
    ode_f(t, ux, uy, k4);
    const float c = h / 6.0f;
#pragma unroll
    for (int i = 0; i < 12; ++i)
        y[i] = y[i] + c * (k1[i] + 2.0f * k2[i] + 2.0f * k3[i] + k4[i]);
}

__global__ void __launch_bounds__(NB)
ode_kernel(const float* __restrict__ act, float* __restrict__ out, int B, int T) {
    // Per-wave private staging, double-buffered: wave w owns
    // lds[buf][w*896 .. w*896+896). 2 x 14336 B total. No inter-wave traffic.
    __shared__ float lds[2][NB * 14];

    const int tid  = threadIdx.x;
    const int lane = tid & 63;
    const int wv   = tid >> 6;
    const int b    = blockIdx.x * NB + tid;   // B % NB == 0

    const float a0 = act[b * 6 + 0];
    const float a1 = act[b * 6 + 1];
    const float a2 = act[b * 6 + 2];

    const float l  = C_L0 + a0;
    const float ld = l * C_D;
    const float ux = a2 / (-ld);
    const float uy = a1 / ld;
    const int   L  = (int)floorf(l / C_DS);

    float y[12];
    y[0] = 0.f; y[1] = 0.f; y[2] = 0.f;
    y[3] = 1.f; y[4] = 0.f; y[5] = 0.f;
    y[6] = 0.f; y[7] = 1.f; y[8] = 0.f;
    y[9] = 0.f; y[10] = 0.f; y[11] = 1.f;

    // Per-wave global base; advance by one output row (B*14 floats) per t.
    f32x4* g = (f32x4*)(out + ((size_t)blockIdx.x * NB + (size_t)wv * 64) * 14);
    const size_t row_stride4 = (size_t)B * 14 / 4;   // f32x4s per (·, B, 14) row

    int buf = 0;
#pragma unroll
    for (int seg = 0; seg < 2; ++seg) {
        for (int t = 0; t < T; ++t) {
            if (t >= 1 && t <= L) rk4_step(y, ux, uy);

            // Stage this lane's 14-float row into the wave's private region.
            // float2 (8B-aligned at lane*56 B); 4-way bank alias, negligible.
            f32x2* dst = (f32x2*)&lds[buf][wv * (64 * 14) + lane * 14];
            dst[0] = (f32x2){y[0],  y[1]};
            dst[1] = (f32x2){y[2],  y[3]};
            dst[2] = (f32x2){y[4],  y[5]};
            dst[3] = (f32x2){y[6],  y[7]};
            dst[4] = (f32x2){y[8],  y[9]};
            dst[5] = (f32x2){y[10], y[11]};
            dst[6] = (f32x2){ux, uy};

            // Wave-local ordering only: all this wave's DS ops (incl. the
            // previous row's ds_reads on the other buffer) complete here.
            // No s_barrier -> no vmcnt(0) drain -> global stores pipeline
            // freely across rows.
            asm volatile("s_waitcnt lgkmcnt(0)" ::: "memory");
            __builtin_amdgcn_sched_barrier(0);

            // Coalesced read-back + streaming store of the wave's contiguous
            // 3584 B chunk: 224 f32x4 over 64 lanes.
            const f32x4* s = (const f32x4*)&lds[buf][wv * (64 * 14)];
            f32x4 v0 = s[lane];
            f32x4 v1 = s[lane + 64];
            f32x4 v2 = s[lane + 128];
            __builtin_nontemporal_store(v0, &g[lane]);
            __builtin_nontemporal_store(v1, &g[lane + 64]);
            __builtin_nontemporal_store(v2, &g[lane + 128]);
            if (lane < 32) {
                f32x4 v3 = s[lane + 192];
                __builtin_nontemporal_store(v3, &g[lane + 192]);
            }

            g += row_stride4;
            buf ^= 1;
        }
    }
}

extern "C" void kernel_launch(void* const* d_in, const int* in_sizes, int n_in,
                              void* d_out, int out_size, void* d_ws, size_t ws_size,
                              hipStream_t stream) {
    const float* act = (const float*)d_in[0];
    float* out = (float*)d_out;
    int B = in_sizes[0] / 6;               // (B, 6) actions
    int T = out_size / (2 * 14 * B);       // output is (2T, B, 14)

    int blocks = B / NB;                   // B = 262144 -> 1024 blocks
    hipLaunchKernelGGL(ode_kernel, dim3(blocks), dim3(NB), 0, stream,
                       act, out, B, T);
}